// Round 5
// baseline (1027.421 us; speedup 1.0000x reference)
//
#include <hip/hip_runtime.h>

#define NROWS 65536
#define KC    1024
#define DD    256
#define ND    (NROWS*DD)      /* 16777216 */
#define KD    (KC*DD)         /* 262144 */

/* output offsets (floats), concatenated in reference return order */
#define O_ZQ   0
#define O_DIST ND
#define O_IDX  (ND+1)
#define O_EMB  (ND+1+NROWS)
#define O_MT   (O_EMB+KD)
#define O_NT   (O_MT+KD)

static __device__ __forceinline__ void minmerge(float& bv, int& bi, float ov, int oi){
  if (ov < bv || (ov == bv && oi < bi)) { bv = ov; bi = oi; }
}

/* STRICT SEQUENTIAL sum of squares (XLA-CPU reduce emission): each square
   rounded (fmul), each add rounded (fadd), ascending order, no FMA. */
static __device__ __forceinline__ float seq_sumsq_256(const float* __restrict__ x){
  float s = __fmul_rn(x[0], x[0]);
  for (int i=1;i<256;i++) s = __fadd_rn(s, __fmul_rn(x[i], x[i]));
  return s;
}

__global__ __launch_bounds__(256,1) void vq_wsq_kernel(const float* __restrict__ W,
                                                       float* __restrict__ wsq){
  const int k = blockIdx.x*256 + threadIdx.x;   /* grid 4 -> 1024 codes */
  wsq[k] = seq_sumsq_256(W + (size_t)k*DD);
}

/* 64 rows per block, full K=1024 codes in 4 chunks of 256.
   256 threads: 8 row-groups (GRp) x 32 code-groups (TX); thread tile 8x8. */
__global__ __launch_bounds__(256,1) void vq_main_kernel(
    const float* __restrict__ ze, const float* __restrict__ W,
    const float* __restrict__ wsq,
    float* __restrict__ out, float* __restrict__ st, float* __restrict__ nt,
    float* __restrict__ dist_acc)
{
  __shared__ float zeS[64*256];   /* 64 KB, row-major */
  __shared__ float wS[16*260];    /* d-chunk x 256 codes, transposed, padded */
  __shared__ float wsqS[256];
  __shared__ float zsqS[64];

  const int tid = threadIdx.x;
  const int blk = blockIdx.x;
  const int GRp = tid >> 5;   /* 0..7  row group */
  const int TX  = tid & 31;   /* 0..31 code group */

  /* stage ze tile: rows [blk*64, blk*64+64) */
  {
    const float* zb = ze + (size_t)blk*64*DD;
    #pragma unroll
    for (int i=0;i<16;i++){
      int f = i*256 + tid;
      *(float4*)&zeS[f*4] = *(const float4*)&zb[(size_t)f*4];
    }
  }
  __syncthreads();

  /* z_sq per row: strict sequential (XLA-CPU reduce order) */
  if (tid < 64) zsqS[tid] = seq_sumsq_256(&zeS[tid*256]);
  /* visibility guaranteed by barriers inside the dc loop before first use */

  float rv[8]; int ri[8];
  #pragma unroll
  for (int e=0;e<8;e++){ rv[e]=3.4e38f; ri[e]=0x7fffffff; }

  /* prefetch first W chunk (nc=0, dc=0): thread t -> code t, d [0,16) */
  float4 wreg[4];
  {
    const float* wp = W + (size_t)tid*DD;
    #pragma unroll
    for (int q=0;q<4;q++) wreg[q] = *(const float4*)(wp + q*4);
  }

  for (int nc=0; nc<4; nc++){
    wsqS[tid] = wsq[nc*256 + tid];

    float acc[64];
    #pragma unroll
    for (int a=0;a<64;a++) acc[a]=0.f;

    for (int dc=0; dc<16; dc++){
      __syncthreads();
      #pragma unroll
      for (int q=0;q<4;q++){
        wS[(4*q+0)*260 + tid] = wreg[q].x;
        wS[(4*q+1)*260 + tid] = wreg[q].y;
        wS[(4*q+2)*260 + tid] = wreg[q].z;
        wS[(4*q+3)*260 + tid] = wreg[q].w;
      }
      __syncthreads();
      int qn = nc*16 + dc + 1;
      if (qn < 64){
        const float* wp = W + (size_t)((qn>>4)*256 + tid)*DD + (qn&15)*16;
        #pragma unroll
        for (int q=0;q<4;q++) wreg[q] = *(const float4*)(wp + q*4);
      }
      /* 16 d-steps, strictly ascending k per accumulator, SEPARATE mul+add
         roundings (Eigen gebp without FMA: acc = acc + round(z*w)) */
      const int dbase = dc*16;
      #pragma unroll
      for (int dd=0; dd<16; dd+=4){
        float4 z4[8];
        #pragma unroll
        for (int e=0;e<8;e++)
          z4[e] = *(const float4*)&zeS[(8*GRp+e)*256 + dbase + dd];
        #pragma unroll
        for (int d2=0; d2<4; d2++){
          float4 wa = *(const float4*)&wS[(dd+d2)*260 + 4*TX];
          float4 wb = *(const float4*)&wS[(dd+d2)*260 + 128 + 4*TX];
          #pragma unroll
          for (int e=0;e<8;e++){
            const float zv = (d2==0)?z4[e].x:(d2==1)?z4[e].y:(d2==2)?z4[e].z:z4[e].w;
            acc[e*8+0] = __fadd_rn(acc[e*8+0], __fmul_rn(zv, wa.x));
            acc[e*8+1] = __fadd_rn(acc[e*8+1], __fmul_rn(zv, wa.y));
            acc[e*8+2] = __fadd_rn(acc[e*8+2], __fmul_rn(zv, wa.z));
            acc[e*8+3] = __fadd_rn(acc[e*8+3], __fmul_rn(zv, wa.w));
            acc[e*8+4] = __fadd_rn(acc[e*8+4], __fmul_rn(zv, wb.x));
            acc[e*8+5] = __fadd_rn(acc[e*8+5], __fmul_rn(zv, wb.y));
            acc[e*8+6] = __fadd_rn(acc[e*8+6], __fmul_rn(zv, wb.z));
            acc[e*8+7] = __fadd_rn(acc[e*8+7], __fmul_rn(zv, wb.w));
          }
        }
      }
    }

    /* chunk argmin: d2 = (z_sq - 2*dot) + w_sq, reference association */
    #pragma unroll
    for (int e=0;e<8;e++){
      const float zs = zsqS[8*GRp + e];
      float bv = 3.4e38f; int bi = 0x7fffffff;
      #pragma unroll
      for (int j=0;j<2;j++){
        #pragma unroll
        for (int m=0;m<4;m++){
          const int cl = 128*j + 4*TX + m;
          const float v = __fadd_rn(__fsub_rn(zs, __fmul_rn(2.0f, acc[e*8 + j*4 + m])),
                                    wsqS[cl]);
          minmerge(bv, bi, v, nc*256 + cl);
        }
      }
      #pragma unroll
      for (int s=1; s<32; s<<=1){
        float ov = __shfl_xor(bv, s);
        int   oi = __shfl_xor(bi, s);
        minmerge(bv, bi, ov, oi);
      }
      minmerge(rv[e], ri[e], bv, bi);
    }
    __syncthreads();
  }

  /* epilogue: per row write zq_st, idx; accumulate dist, st, nt */
  float distp = 0.f;
  #pragma unroll
  for (int e=0;e<8;e++){
    const int r    = 8*GRp + e;
    const int grow = blk*64 + r;
    const int gi   = ri[e];
    const float* wrow = W + (size_t)gi*DD;
    #pragma unroll
    for (int j=0;j<2;j++){
      const int d = 128*j + 4*TX;
      float4 w4 = *(const float4*)(wrow + d);
      float4 z4 = *(const float4*)&zeS[r*256 + d];
      float4 o;
      o.x = z4.x + (w4.x - z4.x);
      o.y = z4.y + (w4.y - z4.y);
      o.z = z4.z + (w4.z - z4.z);
      o.w = z4.w + (w4.w - z4.w);
      *(float4*)&out[(size_t)grow*DD + d] = o;
      float dx;
      dx = w4.x - z4.x; distp += dx*dx;
      dx = w4.y - z4.y; distp += dx*dx;
      dx = w4.z - z4.z; distp += dx*dx;
      dx = w4.w - z4.w; distp += dx*dx;
      atomicAdd(&st[(size_t)gi*DD + d + 0], z4.x);
      atomicAdd(&st[(size_t)gi*DD + d + 1], z4.y);
      atomicAdd(&st[(size_t)gi*DD + d + 2], z4.z);
      atomicAdd(&st[(size_t)gi*DD + d + 3], z4.w);
    }
    if (TX == 0){
      out[O_IDX + grow] = (float)gi;
      atomicAdd(&nt[gi], 1.0f);
    }
  }
  #pragma unroll
  for (int s=1; s<64; s<<=1) distp += __shfl_xor(distp, s);
  if ((tid & 63) == 0) atomicAdd(dist_acc, distp);
}

__global__ __launch_bounds__(256,1) void vq_tail_kernel(
    const float* __restrict__ mt, const float* __restrict__ Nt,
    const float* __restrict__ st, const float* __restrict__ nt,
    const float* __restrict__ dist_acc, float* __restrict__ out)
{
  const float G   = 0.99f;
  const float OMG = (float)(1.0 - 0.99);
  const int i = blockIdx.x*256 + threadIdx.x;
  const int k = i >> 8;
  const float ntn = __fadd_rn(__fmul_rn(G, Nt[k]), __fmul_rn(OMG, nt[k]));
  const float mtn = __fadd_rn(__fmul_rn(G, mt[i]), __fmul_rn(OMG, st[i]));
  out[O_MT  + i] = mtn;
  out[O_EMB + i] = mtn / ntn;
  if (i < KC) out[O_NT + i] = __fadd_rn(__fmul_rn(G, Nt[i]), __fmul_rn(OMG, nt[i]));
  if (i == 0) out[O_DIST] = dist_acc[0] * (1.0f/16777216.0f);
}

extern "C" void kernel_launch(void* const* d_in, const int* in_sizes, int n_in,
                              void* d_out, int out_size, void* d_ws, size_t ws_size,
                              hipStream_t stream){
  const float* ze = (const float*)d_in[0];
  const float* W  = (const float*)d_in[1];
  const float* mt = (const float*)d_in[2];
  const float* Nt = (const float*)d_in[3];
  float* out  = (float*)d_out;
  float* ws   = (float*)d_ws;
  float* st   = ws;                 /* KD  */
  float* nt   = ws + KD;            /* KC  */
  float* dist = ws + KD + KC;       /* 1   */
  float* wsq  = ws + KD + KC + 1;   /* KC  */

  hipMemsetAsync(d_ws, 0, (size_t)(KD + KC + 1)*sizeof(float), stream);
  vq_wsq_kernel <<<KC/256,   256, 0, stream>>>(W, wsq);
  vq_main_kernel<<<NROWS/64, 256, 0, stream>>>(ze, W, wsq, out, st, nt, dist);
  vq_tail_kernel<<<KD/256,   256, 0, stream>>>(mt, Nt, st, nt, dist, out);
}